// Round 24
// baseline (3274.900 us; speedup 1.0000x reference)
//
#include <hip/hip_runtime.h>
#include <hip/hip_fp16.h>

typedef __attribute__((ext_vector_type(8))) short s16x8;
typedef __attribute__((ext_vector_type(8))) _Float16 f16x8;
typedef __attribute__((ext_vector_type(4))) float f32x4;

// ---------------------------------------------------------------------------
// device helper: one cvt unit = 8 floats -> 8 halves
// ---------------------------------------------------------------------------
__device__ __forceinline__ void cvt_unit(const float4* __restrict__ p4,
                                         __half* __restrict__ out, long j) {
  float4 a = p4[j * 2];
  float4 b = p4[j * 2 + 1];
  union { s16x8 v; __half2 h2[4]; } w;
  w.h2[0] = __floats2half2_rn(a.x, a.y);
  w.h2[1] = __floats2half2_rn(a.z, a.w);
  w.h2[2] = __floats2half2_rn(b.x, b.y);
  w.h2[3] = __floats2half2_rn(b.z, b.w);
  *(s16x8*)(out + j * 8) = w.v;
}

// ---------------------------------------------------------------------------
// fp32 -> fp16 conversion (standalone; only for chunk 0 where folds race)
// ---------------------------------------------------------------------------
__global__ void cvt_f32_to_f16_kernel(const float* __restrict__ in,
                                      __half* __restrict__ out, long n8) {
  long i = (long)blockIdx.x * blockDim.x + threadIdx.x;
  long stride = (long)gridDim.x * blockDim.x;
  const float4* p4 = (const float4*)in;
  for (long j = i; j < n8; j += stride) cvt_unit(p4, out, j);
}

// ---------------------------------------------------------------------------
// prep: pack all 3 weight matrices + cvt of the first (highest) chunk.
// ---------------------------------------------------------------------------
__device__ __forceinline__ void pack_unit(const int* __restrict__ q,
                                          uint32_t* __restrict__ p, long i) {
  int4 a = ((const int4*)q)[2 * i];
  int4 b = ((const int4*)q)[2 * i + 1];
  p[i] = (uint32_t)a.x | ((uint32_t)a.y << 4) | ((uint32_t)a.z << 8) |
         ((uint32_t)a.w << 12) | ((uint32_t)b.x << 16) |
         ((uint32_t)b.y << 20) | ((uint32_t)b.z << 24) |
         ((uint32_t)b.w << 28);
}

__global__ void prep_kernel(const int* __restrict__ qd, uint32_t* __restrict__ Pd,
                            const int* __restrict__ qg, uint32_t* __restrict__ Pg,
                            const int* __restrict__ qu, uint32_t* __restrict__ Pu,
                            long n8,
                            const float* __restrict__ xc, __half* __restrict__ wsx,
                            long ncvt) {
  long i = (long)blockIdx.x * blockDim.x + threadIdx.x;
  long stride = (long)gridDim.x * blockDim.x;
  const long total = 3 * n8 + ncvt;
  const float4* p4 = (const float4*)xc;
  for (; i < total; i += stride) {
    if (i < n8) pack_unit(qd, Pd, i);
    else if (i < 2 * n8) pack_unit(qg, Pg, i - n8);
    else if (i < 3 * n8) pack_unit(qu, Pu, i - 2 * n8);
    else cvt_unit(p4, wsx, i - 3 * n8);
  }
}

// ---------------------------------------------------------------------------
// Dequant: f16(64+q)=0x5400|(q<<4);  w = b*s - (64+z)*s
// ---------------------------------------------------------------------------
__device__ __forceinline__ s16x8 dq_compute(int4 q0, int4 q1, float s, float z) {
  __half hs = __float2half(s);
  __half2 s2 = __halves2half2(hs, hs);
  __half hc = __float2half(-(64.f + z) * s);
  __half2 c2 = __halves2half2(hc, hc);
  uint32_t b0 = 0x54005400u + ((uint32_t)q0.x << 4) + ((uint32_t)q0.y << 20);
  uint32_t b1 = 0x54005400u + ((uint32_t)q0.z << 4) + ((uint32_t)q0.w << 20);
  uint32_t b2 = 0x54005400u + ((uint32_t)q1.x << 4) + ((uint32_t)q1.y << 20);
  uint32_t b3 = 0x54005400u + ((uint32_t)q1.z << 4) + ((uint32_t)q1.w << 20);
  union { s16x8 v; __half2 h2[4]; } w;
  w.h2[0] = __hfma2(*(__half2*)&b0, s2, c2);
  w.h2[1] = __hfma2(*(__half2*)&b1, s2, c2);
  w.h2[2] = __hfma2(*(__half2*)&b2, s2, c2);
  w.h2[3] = __hfma2(*(__half2*)&b3, s2, c2);
  return w.v;
}

__device__ __forceinline__ s16x8 dq8(uint32_t w, __half2 s2, __half2 c2) {
  union { s16x8 v; __half2 h2[4]; } r;
#pragma unroll
  for (int i = 0; i < 4; ++i) {
    uint32_t t = (w >> (8 * i)) & 0xFFu;
    uint32_t b = 0x54005400u + ((t & 15u) << 4) + ((t >> 4) << 20);
    r.h2[i] = __hfma2(*(__half2*)&b, s2, c2);
  }
  return r.v;
}

// bijective XCD swizzle (m204)
__device__ __forceinline__ int xcd_swz(int w0, int nwg) {
  const int q = nwg >> 3, r = nwg & 7;
  const int xcd = w0 & 7, idx = w0 >> 3;
  const int base = (xcd < r) ? xcd * (q + 1) : r * (q + 1) + (xcd - r) * q;
  return base + idx;
}

// ---------------------------------------------------------------------------
// FUSED gate+up GEMM (+ optional cvt tail blocks for the next chunk's x).
// ---------------------------------------------------------------------------
template <int PKG, int PKU>
__global__ __launch_bounds__(512, 2)
void gateup_kernel(const __half* __restrict__ Xh,
                   const int* __restrict__ Qg, const uint32_t* __restrict__ Pg,
                   const int* __restrict__ Qu, const uint32_t* __restrict__ Pu,
                   const float* __restrict__ Sg, const float* __restrict__ Zg,
                   const float* __restrict__ Su, const float* __restrict__ Zu,
                   __half* __restrict__ Pan, int mbs,
                   const float* __restrict__ xnext, __half* __restrict__ wsxn,
                   long ncvt) {
  constexpr int H = 4096, I = 11008, G = 32;
  const int wg = xcd_swz(blockIdx.x, gridDim.x);
  const int gemmBlocks = mbs * (I / 128);
  if (wg >= gemmBlocks) {
    const int ncb = gridDim.x - gemmBlocks;
    long i = (long)(wg - gemmBlocks) * 512 + threadIdx.x;
    long stride = (long)ncb * 512;
    const float4* p4 = (const float4*)xnext;
    for (long j = i; j < ncvt; j += stride) cvt_unit(p4, wsxn, j);
    return;
  }
  const int mb = wg % mbs;
  const int nb = wg / mbs;
  const int m0 = mb * 256;
  const int n0 = nb * 128;
  const int tid = threadIdx.x;
  const int lane = tid & 63;
  const int wave = tid >> 6;
  const int wm = (wave >> 1) * 64, wn = (wave & 1) * 64;
  const int l15 = lane & 15, lq = lane >> 4;
  const int rsw = (l15 & 7) << 3;

  __shared__ __half As[2][256][64];
  __shared__ __half Bg[2][128][64];
  __shared__ __half Bu[2][128][64];

  f32x4 accg[4][4], accu[4][4];
#pragma unroll
  for (int i = 0; i < 4; ++i)
#pragma unroll
    for (int j = 0; j < 4; ++j) {
      accg[i][j] = {0.f, 0.f, 0.f, 0.f};
      accu[i][j] = {0.f, 0.f, 0.f, 0.f};
    }

  const int arowD = tid >> 3;
  const int acolD = (((tid & 7) ^ ((tid >> 3) & 7)) << 3);
  const int qrow = tid >> 2, qcol0 = (tid & 3) * 16, qsw = (qrow & 7) << 3;
  const int*      qPg = Qg + (size_t)(n0 + qrow) * H + qcol0;
  const int*      qPu = Qu + (size_t)(n0 + qrow) * H + qcol0;
  const uint32_t* pPg = Pg + (size_t)(n0 + qrow) * (H / 8) + (tid & 3) * 2;
  const uint32_t* pPu = Pu + (size_t)(n0 + qrow) * (H / 8) + (tid & 3) * 2;
  const float* sPg = Sg + (size_t)(n0 + qrow) * G;
  const float* zPg = Zg + (size_t)(n0 + qrow) * G;
  const float* sPu = Su + (size_t)(n0 + qrow) * G;
  const float* zPu = Zu + (size_t)(n0 + qrow) * G;

  int4 qG[4], qU[4];
  uint32_t wG0, wG1, wU0, wU1;
  float sG, zG, sU, zU;

#define STAGE_A(buf, kk)                                              \
  {                                                                   \
    const int _k = (kk);                                              \
    _Pragma("unroll")                                                 \
    for (int c = 0; c < 4; ++c) {                                     \
      const __half* src = Xh + (size_t)(m0 + c * 64 + arowD) * H + _k + acolD; \
      __half* dst = &As[buf][0][0] + (size_t)(c * 512 + tid) * 8;     \
      __builtin_amdgcn_global_load_lds((const __attribute__((address_space(1))) void*)src, \
                                       (__attribute__((address_space(3))) void*)dst, 16, 0, 0); \
    }                                                                 \
  }
#define LOAD_Q(kk)                                                    \
  {                                                                   \
    const int _k = (kk);                                              \
    if (PKG) { wG0 = pPg[_k >> 3]; wG1 = pPg[(_k >> 3) + 1]; }        \
    else {                                                            \
      _Pragma("unroll")                                               \
      for (int i = 0; i < 4; ++i) qG[i] = ((const int4*)(qPg + _k))[i]; \
    }                                                                 \
    if (PKU) { wU0 = pPu[_k >> 3]; wU1 = pPu[(_k >> 3) + 1]; }        \
    else {                                                            \
      _Pragma("unroll")                                               \
      for (int i = 0; i < 4; ++i) qU[i] = ((const int4*)(qPu + _k))[i]; \
    }                                                                 \
    sG = sPg[_k >> 7]; zG = zPg[_k >> 7];                             \
    sU = sPu[_k >> 7]; zU = zPu[_k >> 7];                             \
  }
#define WRITE_B(buf)                                                  \
  {                                                                   \
    if (PKG) {                                                        \
      __half h1 = __float2half(sG);                                   \
      __half2 s2 = __halves2half2(h1, h1);                            \
      __half h2 = __float2half(-(64.f + zG) * sG);                    \
      __half2 c2 = __halves2half2(h2, h2);                            \
      *(s16x8*)&Bg[buf][qrow][(qcol0 + 0) ^ qsw] = dq8(wG0, s2, c2);  \
      *(s16x8*)&Bg[buf][qrow][(qcol0 + 8) ^ qsw] = dq8(wG1, s2, c2);  \
    } else {                                                          \
      *(s16x8*)&Bg[buf][qrow][(qcol0 + 0) ^ qsw] = dq_compute(qG[0], qG[1], sG, zG); \
      *(s16x8*)&Bg[buf][qrow][(qcol0 + 8) ^ qsw] = dq_compute(qG[2], qG[3], sG, zG); \
    }                                                                 \
    if (PKU) {                                                        \
      __half h3 = __float2half(sU);                                   \
      __half2 s3 = __halves2half2(h3, h3);                            \
      __half h4 = __float2half(-(64.f + zU) * sU);                    \
      __half2 c3 = __halves2half2(h4, h4);                            \
      *(s16x8*)&Bu[buf][qrow][(qcol0 + 0) ^ qsw] = dq8(wU0, s3, c3);  \
      *(s16x8*)&Bu[buf][qrow][(qcol0 + 8) ^ qsw] = dq8(wU1, s3, c3);  \
    } else {                                                          \
      *(s16x8*)&Bu[buf][qrow][(qcol0 + 0) ^ qsw] = dq_compute(qU[0], qU[1], sU, zU); \
      *(s16x8*)&Bu[buf][qrow][(qcol0 + 8) ^ qsw] = dq_compute(qU[2], qU[3], sU, zU); \
    }                                                                 \
  }
#define MFMA_BUF(buf)                                                 \
  {                                                                   \
    __builtin_amdgcn_s_setprio(1);                                    \
    _Pragma("unroll")                                                 \
    for (int kk = 0; kk < 2; ++kk) {                                  \
      const int cbase = (kk * 32 + lq * 8) ^ rsw;                     \
      f16x8 af[4];                                                    \
      _Pragma("unroll")                                               \
      for (int i = 0; i < 4; ++i)                                     \
        af[i] = *(const f16x8*)&As[buf][wm + i * 16 + l15][cbase];    \
      _Pragma("unroll")                                               \
      for (int j = 0; j < 4; ++j) {                                   \
        f16x8 bg = *(const f16x8*)&Bg[buf][wn + j * 16 + l15][cbase]; \
        f16x8 bu = *(const f16x8*)&Bu[buf][wn + j * 16 + l15][cbase]; \
        _Pragma("unroll")                                             \
        for (int i = 0; i < 4; ++i) {                                 \
          accg[i][j] = __builtin_amdgcn_mfma_f32_16x16x32_f16(af[i], bg, accg[i][j], 0, 0, 0); \
          accu[i][j] = __builtin_amdgcn_mfma_f32_16x16x32_f16(af[i], bu, accu[i][j], 0, 0, 0); \
        }                                                             \
      }                                                               \
    }                                                                 \
    __builtin_amdgcn_s_setprio(0);                                    \
  }

  const int nt = H / 64;
  STAGE_A(0, 0)
  LOAD_Q(0)
  WRITE_B(0)
  __syncthreads();

  int p = 0;
  for (int t = 0; t < nt; ++t) {
    if (t + 1 < nt) {
      STAGE_A(p ^ 1, (t + 1) * 64)
      LOAD_Q((t + 1) * 64)
    }
    MFMA_BUF(p)
    if (t + 1 < nt) WRITE_B(p ^ 1)
    __syncthreads();
    p ^= 1;
  }
#undef STAGE_A
#undef LOAD_Q
#undef WRITE_B
#undef MFMA_BUF

#pragma unroll
  for (int i = 0; i < 4; ++i)
#pragma unroll
    for (int j = 0; j < 4; ++j)
#pragma unroll
      for (int r = 0; r < 4; ++r) {
        const int row = m0 + wm + i * 16 + lq * 4 + r;
        const int col = n0 + wn + j * 16 + l15;
        float g = accg[i][j][r];
        float u = accu[i][j][r];
        float hv = (g / (1.f + __expf(-g))) * u;
        Pan[(size_t)row * I + col] = __float2half(hv);
      }
}

// ---------------------------------------------------------------------------
// Down GEMM (+ optional cvt tail blocks).
// ---------------------------------------------------------------------------
template <int PK>
__global__ __launch_bounds__(512, 2)
void down_kernel(const __half* __restrict__ Hws,
                 const int* __restrict__ Qd, const uint32_t* __restrict__ QdP,
                 const float* __restrict__ Sd, const float* __restrict__ Zd,
                 float* __restrict__ Out, int mbs,
                 const float* __restrict__ xnext, __half* __restrict__ wsxn,
                 long ncvt) {
  constexpr int K = 11008, N = 4096, G = 86;
  const int wg = xcd_swz(blockIdx.x, gridDim.x);
  const int gemmBlocks = mbs * 32;
  if (wg >= gemmBlocks) {
    const int ncb = gridDim.x - gemmBlocks;
    long i = (long)(wg - gemmBlocks) * 512 + threadIdx.x;
    long stride = (long)ncb * 512;
    const float4* p4 = (const float4*)xnext;
    for (long j = i; j < ncvt; j += stride) cvt_unit(p4, wsxn, j);
    return;
  }
  const int mb = wg % mbs;
  const int nb = wg / mbs;
  const int m0 = mb * 256, n0 = nb * 128;
  const int tid = threadIdx.x;
  const int lane = tid & 63;
  const int wave = tid >> 6;
  const int wm = (wave >> 1) * 64, wn = (wave & 1) * 64;
  const int l15 = lane & 15, lq = lane >> 4;
  const int rsw = (l15 & 7) << 3;

  __shared__ __half As[2][256][64];
  __shared__ __half Bs[2][128][64];

  f32x4 acc[4][4];
#pragma unroll
  for (int i = 0; i < 4; ++i)
#pragma unroll
    for (int j = 0; j < 4; ++j) acc[i][j] = {0.f, 0.f, 0.f, 0.f};

  const int arowD = tid >> 3;
  const int acolD = (((tid & 7) ^ ((tid >> 3) & 7)) << 3);
  const int qrow = tid >> 2, qcol0 = (tid & 3) * 16, qsw = (qrow & 7) << 3;
  const int*      qP  = Qd  + (size_t)(n0 + qrow) * K + qcol0;
  const uint32_t* qPp = QdP + (size_t)(n0 + qrow) * (K / 8) + (tid & 3) * 2;
  const float* sP = Sd + (size_t)(n0 + qrow) * G;
  const float* zP = Zd + (size_t)(n0 + qrow) * G;

  int4 qA[4], qB[4];
  uint32_t wA0, wA1, wB0, wB1;
  float sA, zA, sB, zB;

#define STAGE_A(buf, kk)                                              \
  {                                                                   \
    const int _k = (kk);                                              \
    _Pragma("unroll")                                                 \
    for (int c = 0; c < 4; ++c) {                                     \
      const __half* src = Hws + (size_t)(m0 + c * 64 + arowD) * K + _k + acolD; \
      __half* dst = &As[buf][0][0] + (size_t)(c * 512 + tid) * 8;     \
      __builtin_amdgcn_global_load_lds((const __attribute__((address_space(1))) void*)src, \
                                       (__attribute__((address_space(3))) void*)dst, 16, 0, 0); \
    }                                                                 \
  }
#define LOAD_Q(set, kk)                                               \
  {                                                                   \
    const int _k = (kk);                                              \
    if (PK) {                                                         \
      w##set##0 = qPp[_k >> 3]; w##set##1 = qPp[(_k >> 3) + 1];       \
    } else {                                                          \
      _Pragma("unroll")                                               \
      for (int i = 0; i < 4; ++i) q##set[i] = ((const int4*)(qP + _k))[i]; \
    }                                                                 \
    s##set = sP[_k >> 7]; z##set = zP[_k >> 7];                       \
  }
#define WRITE_B(buf, set)                                             \
  {                                                                   \
    if (PK) {                                                         \
      __half hs = __float2half(s##set);                               \
      __half2 s2 = __halves2half2(hs, hs);                            \
      __half hc = __float2half(-(64.f + z##set) * s##set);            \
      __half2 c2 = __halves2half2(hc, hc);                            \
      *(s16x8*)&Bs[buf][qrow][(qcol0 + 0) ^ qsw] = dq8(w##set##0, s2, c2); \
      *(s16x8*)&Bs[buf][qrow][(qcol0 + 8) ^ qsw] = dq8(w##set##1, s2, c2); \
    } else {                                                          \
      *(s16x8*)&Bs[buf][qrow][(qcol0 + 0) ^ qsw] = dq_compute(q##set[0], q##set[1], s##set, z##set); \
      *(s16x8*)&Bs[buf][qrow][(qcol0 + 8) ^ qsw] = dq_compute(q##set[2], q##set[3], s##set, z##set); \
    }                                                                 \
  }
#define MFMA_BUF(buf)                                                 \
  {                                                                   \
    __builtin_amdgcn_s_setprio(1);                                    \
    _Pragma("unroll")                                                 \
    for (int kk = 0; kk < 2; ++kk) {                                  \
      const int cbase = (kk * 32 + lq * 8) ^ rsw;                     \
      f16x8 af[4];                                                    \
      _Pragma("unroll")                                               \
      for (int i = 0; i < 4; ++i)                                     \
        af[i] = *(const f16x8*)&As[buf][wm + i * 16 + l15][cbase];    \
      _Pragma("unroll")                                               \
      for (int j = 0; j < 4; ++j) {                                   \
        f16x8 bf = *(const f16x8*)&Bs[buf][wn + j * 16 + l15][cbase]; \
        _Pragma("unroll")                                             \
        for (int i = 0; i < 4; ++i)                                   \
          acc[i][j] = __builtin_amdgcn_mfma_f32_16x16x32_f16(af[i], bf, acc[i][j], 0, 0, 0); \
      }                                                               \
    }                                                                 \
    __builtin_amdgcn_s_setprio(0);                                    \
  }

  const int nt = K / 64;
  STAGE_A(0, 0)
  LOAD_Q(A, 0)
  LOAD_Q(B, 64)
  WRITE_B(0, A)
  __syncthreads();

  for (int t = 0; t < nt; t += 2) {
    if (t + 1 < nt) STAGE_A(1, (t + 1) * 64)
    if (t + 2 < nt) LOAD_Q(A, (t + 2) * 64)
    MFMA_BUF(0)
    if (t + 1 < nt) WRITE_B(1, B)
    __syncthreads();
    if (t + 2 < nt) STAGE_A(0, (t + 2) * 64)
    if (t + 3 < nt) LOAD_Q(B, (t + 3) * 64)
    MFMA_BUF(1)
    if (t + 2 < nt) WRITE_B(0, A)
    __syncthreads();
  }
#undef STAGE_A
#undef LOAD_Q
#undef WRITE_B
#undef MFMA_BUF

#pragma unroll
  for (int i = 0; i < 4; ++i)
#pragma unroll
    for (int j = 0; j < 4; ++j)
#pragma unroll
      for (int r = 0; r < 4; ++r) {
        const int row = m0 + wm + i * 16 + lq * 4 + r;
        const int col = n0 + wn + j * 16 + l15;
        Out[(size_t)row * N + col] = acc[i][j][r];
      }
}

// ---------------------------------------------------------------------------
extern "C" void kernel_launch(void* const* d_in, const int* in_sizes, int n_in,
                              void* d_out, int out_size, void* d_ws, size_t ws_size,
                              hipStream_t stream) {
  const float* x  = (const float*)d_in[0];
  const int* qg   = (const int*)d_in[1];
  const int* qu   = (const int*)d_in[2];
  const int* qd   = (const int*)d_in[3];
  const float* sg = (const float*)d_in[4];
  const float* zg = (const float*)d_in[5];
  const float* su = (const float*)d_in[6];
  const float* zu = (const float*)d_in[7];
  const float* sd = (const float*)d_in[8];
  const float* zd = (const float*)d_in[9];
  float* out = (float*)d_out;

  const int M = 8192, H = 4096, I = 11008;
  const long N8 = (long)I * H / 8;

  // Packed at d_out bottom; chunks DESCENDING.
  // Pd rows 0..1375, Pg 1376..2751, Pu 2752..4127.
  const int PD_LO = 0, PD_HI = 1376, PG_LO = 1376, PG_HI = 2752,
            PU_LO = 2752, PU_HI = 4128;
  uint32_t* Pd = (uint32_t*)d_out;
  uint32_t* Pg = Pd + N8;
  uint32_t* Pu = Pg + N8;

  long mc = (long)(ws_size / ((size_t)I * 2));
  mc &= ~255L;
  if (mc > 2048) mc = 2048;
  if (mc < 256) mc = 256;
  const int Mc = (int)mc;
  __half* wsh = (__half*)d_ws;

  int mb_arr[64], mbs_arr[64];
  int nch = 0;
  for (int mb = 0; mb < M; mb += Mc) {
    mb_arr[nch] = mb;
    mbs_arr[nch] = ((M - mb < Mc) ? (M - mb) : Mc) / 256;
    ++nch;
  }

  auto wsx_lo = [&](int c) {  // wsx(c) occupies out rows [wsx_lo, mb+rows)
    const int rows = mbs_arr[c] * 256;
    return mb_arr[c] + rows - rows / 2;
  };
  auto wsx_ptr = [&](int c) { return (__half*)(out + (size_t)wsx_lo(c) * H); };
  auto overlap = [](int a0, int a1, int b0, int b1) {
    return a0 < b1 && b0 < a1;
  };

  // prep: 3 packs + cvt of highest chunk.
  {
    const int c0 = nch - 1;
    prep_kernel<<<2048, 256, 0, stream>>>(
        qd, Pd, qg, Pg, qu, Pu, N8,
        x + (size_t)mb_arr[c0] * H, wsx_ptr(c0),
        (long)mbs_arr[c0] * 256 * H / 8);
  }

  int destr = M;
  // wsx(top chunk) clobber from prep:
  if (wsx_lo(nch - 1) < destr) destr = wsx_lo(nch - 1);

  for (int c = nch - 1; c >= 0; --c) {
    const int mbase = mb_arr[c];
    const int mbs = mbs_arr[c];
    const bool g_pk = (PG_HI <= destr);
    const bool u_pk = (PU_HI <= destr);
    const bool d_pk = (PD_HI <= destr) && (PD_HI <= mbase);

    // Can cvt(c-1) ride in gateup(c) / down(c)?  (no overlap with regions read)
    bool foldG = false, foldD = false;
    long ncvt = 0;
    const float* xn = x;
    __half* wsxn = nullptr;
    if (c > 0) {
      const int lo = wsx_lo(c - 1);
      const int hi = mb_arr[c - 1] + mbs_arr[c - 1] * 256;
      ncvt = (long)mbs_arr[c - 1] * 256 * H / 8;
      xn = x + (size_t)mb_arr[c - 1] * H;
      wsxn = wsx_ptr(c - 1);
      foldG = !((g_pk && overlap(lo, hi, PG_LO, PG_HI)) ||
                (u_pk && overlap(lo, hi, PU_LO, PU_HI)));
      foldD = !(d_pk && overlap(lo, hi, PD_LO, PD_HI));
    }

    // gateup(c) [+ cvt tail if foldG]
    {
      const int gb = mbs * (I / 128);
      const int grid = foldG ? gb + 80 : gb;
      const long nc = foldG ? ncvt : 0;
      if (g_pk && u_pk)
        gateup_kernel<1, 1><<<grid, 512, 0, stream>>>(
            wsx_ptr(c), qg, Pg, qu, Pu, sg, zg, su, zu, wsh, mbs, xn, wsxn, nc);
      else if (g_pk)
        gateup_kernel<1, 0><<<grid, 512, 0, stream>>>(
            wsx_ptr(c), qg, Pg, qu, Pu, sg, zg, su, zu, wsh, mbs, xn, wsxn, nc);
      else
        gateup_kernel<0, 0><<<grid, 512, 0, stream>>>(
            wsx_ptr(c), qg, Pg, qu, Pu, sg, zg, su, zu, wsh, mbs, xn, wsxn, nc);
    }

    // down(c) [+ cvt tail if !foldG && foldD]
    {
      const bool fD = !foldG && foldD && (c > 0);
      const int gb = mbs * 32;
      const int grid = fD ? gb + 80 : gb;
      const long nc = fD ? ncvt : 0;
      if (d_pk)
        down_kernel<1><<<grid, 512, 0, stream>>>(
            wsh, qd, Pd, sd, zd, out + (size_t)mbase * H, mbs, xn, wsxn, nc);
      else
        down_kernel<0><<<grid, 512, 0, stream>>>(
            wsh, qd, Pd, sd, zd, out + (size_t)mbase * H, mbs, xn, wsxn, nc);
    }

    // standalone cvt if neither host was safe
    if (c > 0 && !foldG && !foldD)
      cvt_f32_to_f16_kernel<<<1024, 256, 0, stream>>>(xn, wsxn, ncvt);

    // clobber accounting: down(c) wrote chunk c; cvt(c-1) wrote wsx(c-1)
    if (mbase < destr) destr = mbase;
    if (c > 0 && wsx_lo(c - 1) < destr) destr = wsx_lo(c - 1);
  }
}

// Round 25
// 3036.469 us; speedup vs baseline: 1.0785x; 1.0785x over previous
//
#include <hip/hip_runtime.h>
#include <hip/hip_fp16.h>

typedef __attribute__((ext_vector_type(8))) short s16x8;
typedef __attribute__((ext_vector_type(8))) _Float16 f16x8;
typedef __attribute__((ext_vector_type(4))) float f32x4;

// ---------------------------------------------------------------------------
// fp32 -> fp16 conversion (vectorized, grid-stride)
// ---------------------------------------------------------------------------
__global__ void cvt_f32_to_f16_kernel(const float* __restrict__ in,
                                      __half* __restrict__ out, long n) {
  long i = (long)blockIdx.x * blockDim.x + threadIdx.x;
  long stride = (long)gridDim.x * blockDim.x;
  const float4* p4 = (const float4*)in;
  for (long j = i; j * 8 < n; j += stride) {
    float4 a = p4[j * 2];
    float4 b = p4[j * 2 + 1];
    union { s16x8 v; __half2 h2[4]; } w;
    w.h2[0] = __floats2half2_rn(a.x, a.y);
    w.h2[1] = __floats2half2_rn(a.z, a.w);
    w.h2[2] = __floats2half2_rn(b.x, b.y);
    w.h2[3] = __floats2half2_rn(b.z, b.w);
    *(s16x8*)(out + j * 8) = w.v;
  }
}

// ---------------------------------------------------------------------------
// Pack 8 int32 (values 0..15) -> 1 uint32 of nibbles (k ascending from LSB).
// ---------------------------------------------------------------------------
__global__ void pack_kernel(const int* __restrict__ q, uint32_t* __restrict__ p,
                            long n8) {
  long i = (long)blockIdx.x * blockDim.x + threadIdx.x;
  long stride = (long)gridDim.x * blockDim.x;
  for (; i < n8; i += stride) {
    int4 a = ((const int4*)q)[2 * i];
    int4 b = ((const int4*)q)[2 * i + 1];
    uint32_t w = (uint32_t)a.x | ((uint32_t)a.y << 4) | ((uint32_t)a.z << 8) |
                 ((uint32_t)a.w << 12) | ((uint32_t)b.x << 16) |
                 ((uint32_t)b.y << 20) | ((uint32_t)b.z << 24) |
                 ((uint32_t)b.w << 28);
    p[i] = w;
  }
}

// ---------------------------------------------------------------------------
// Dequant: f16(64+q)=0x5400|(q<<4);  w = b*s - (64+z)*s
// ---------------------------------------------------------------------------
__device__ __forceinline__ s16x8 dq_compute(int4 q0, int4 q1, float s, float z) {
  __half hs = __float2half(s);
  __half2 s2 = __halves2half2(hs, hs);
  __half hc = __float2half(-(64.f + z) * s);
  __half2 c2 = __halves2half2(hc, hc);
  uint32_t b0 = 0x54005400u + ((uint32_t)q0.x << 4) + ((uint32_t)q0.y << 20);
  uint32_t b1 = 0x54005400u + ((uint32_t)q0.z << 4) + ((uint32_t)q0.w << 20);
  uint32_t b2 = 0x54005400u + ((uint32_t)q1.x << 4) + ((uint32_t)q1.y << 20);
  uint32_t b3 = 0x54005400u + ((uint32_t)q1.z << 4) + ((uint32_t)q1.w << 20);
  union { s16x8 v; __half2 h2[4]; } w;
  w.h2[0] = __hfma2(*(__half2*)&b0, s2, c2);
  w.h2[1] = __hfma2(*(__half2*)&b1, s2, c2);
  w.h2[2] = __hfma2(*(__half2*)&b2, s2, c2);
  w.h2[3] = __hfma2(*(__half2*)&b3, s2, c2);
  return w.v;
}

// 8 weights from one packed u32 (nibbles ascending)
__device__ __forceinline__ s16x8 dq8(uint32_t w, __half2 s2, __half2 c2) {
  union { s16x8 v; __half2 h2[4]; } r;
#pragma unroll
  for (int i = 0; i < 4; ++i) {
    uint32_t t = (w >> (8 * i)) & 0xFFu;
    uint32_t b = 0x54005400u + ((t & 15u) << 4) + ((t >> 4) << 20);
    r.h2[i] = __hfma2(*(__half2*)&b, s2, c2);
  }
  return r.v;
}

// bijective XCD swizzle (m204)
__device__ __forceinline__ int xcd_swz(int w0, int nwg) {
  const int q = nwg >> 3, r = nwg & 7;
  const int xcd = w0 & 7, idx = w0 >> 3;
  const int base = (xcd < r) ? xcd * (q + 1) : r * (q + 1) + (xcd - r) * q;
  return base + idx;
}

// ---------------------------------------------------------------------------
// FUSED gate+up GEMM: h = silu(x@Wg^T) * (x@Wu^T).  Per-matrix packing flags.
// A staged once via global_load_lds (dbuf); Bg+Bu dequant to LDS (dbuf).
// BM=256, BN=128, BK=64. LDS 128 KB, 1 block/CU.
// ---------------------------------------------------------------------------
template <int PKG, int PKU>
__global__ __launch_bounds__(512, 2)
void gateup_kernel(const __half* __restrict__ Xh,
                   const int* __restrict__ Qg, const uint32_t* __restrict__ Pg,
                   const int* __restrict__ Qu, const uint32_t* __restrict__ Pu,
                   const float* __restrict__ Sg, const float* __restrict__ Zg,
                   const float* __restrict__ Su, const float* __restrict__ Zu,
                   __half* __restrict__ Pan, int mbs) {
  constexpr int H = 4096, I = 11008, G = 32;
  const int wg = xcd_swz(blockIdx.x, gridDim.x);
  const int mb = wg % mbs;
  const int nb = wg / mbs;
  const int m0 = mb * 256;
  const int n0 = nb * 128;
  const int tid = threadIdx.x;
  const int lane = tid & 63;
  const int wave = tid >> 6;
  const int wm = (wave >> 1) * 64, wn = (wave & 1) * 64;
  const int l15 = lane & 15, lq = lane >> 4;
  const int rsw = (l15 & 7) << 3;

  __shared__ __half As[2][256][64];   // 64 KB
  __shared__ __half Bg[2][128][64];   // 32 KB
  __shared__ __half Bu[2][128][64];   // 32 KB

  f32x4 accg[4][4], accu[4][4];
#pragma unroll
  for (int i = 0; i < 4; ++i)
#pragma unroll
    for (int j = 0; j < 4; ++j) {
      accg[i][j] = {0.f, 0.f, 0.f, 0.f};
      accu[i][j] = {0.f, 0.f, 0.f, 0.f};
    }

  const int arowD = tid >> 3;
  const int acolD = (((tid & 7) ^ ((tid >> 3) & 7)) << 3);
  const int qrow = tid >> 2, qcol0 = (tid & 3) * 16, qsw = (qrow & 7) << 3;
  const int*      qPg = Qg + (size_t)(n0 + qrow) * H + qcol0;
  const int*      qPu = Qu + (size_t)(n0 + qrow) * H + qcol0;
  const uint32_t* pPg = Pg + (size_t)(n0 + qrow) * (H / 8) + (tid & 3) * 2;
  const uint32_t* pPu = Pu + (size_t)(n0 + qrow) * (H / 8) + (tid & 3) * 2;
  const float* sPg = Sg + (size_t)(n0 + qrow) * G;
  const float* zPg = Zg + (size_t)(n0 + qrow) * G;
  const float* sPu = Su + (size_t)(n0 + qrow) * G;
  const float* zPu = Zu + (size_t)(n0 + qrow) * G;

  int4 qG[4], qU[4];
  uint32_t wG0, wG1, wU0, wU1;
  float sG, zG, sU, zU;

#define STAGE_A(buf, kk)                                              \
  {                                                                   \
    const int _k = (kk);                                              \
    _Pragma("unroll")                                                 \
    for (int c = 0; c < 4; ++c) {                                     \
      const __half* src = Xh + (size_t)(m0 + c * 64 + arowD) * H + _k + acolD; \
      __half* dst = &As[buf][0][0] + (size_t)(c * 512 + tid) * 8;     \
      __builtin_amdgcn_global_load_lds((const __attribute__((address_space(1))) void*)src, \
                                       (__attribute__((address_space(3))) void*)dst, 16, 0, 0); \
    }                                                                 \
  }
#define LOAD_Q(kk)                                                    \
  {                                                                   \
    const int _k = (kk);                                              \
    if (PKG) { wG0 = pPg[_k >> 3]; wG1 = pPg[(_k >> 3) + 1]; }        \
    else {                                                            \
      _Pragma("unroll")                                               \
      for (int i = 0; i < 4; ++i) qG[i] = ((const int4*)(qPg + _k))[i]; \
    }                                                                 \
    if (PKU) { wU0 = pPu[_k >> 3]; wU1 = pPu[(_k >> 3) + 1]; }        \
    else {                                                            \
      _Pragma("unroll")                                               \
      for (int i = 0; i < 4; ++i) qU[i] = ((const int4*)(qPu + _k))[i]; \
    }                                                                 \
    sG = sPg[_k >> 7]; zG = zPg[_k >> 7];                             \
    sU = sPu[_k >> 7]; zU = zPu[_k >> 7];                             \
  }
#define WRITE_B(buf)                                                  \
  {                                                                   \
    if (PKG) {                                                        \
      __half h1 = __float2half(sG);                                   \
      __half2 s2 = __halves2half2(h1, h1);                            \
      __half h2 = __float2half(-(64.f + zG) * sG);                    \
      __half2 c2 = __halves2half2(h2, h2);                            \
      *(s16x8*)&Bg[buf][qrow][(qcol0 + 0) ^ qsw] = dq8(wG0, s2, c2);  \
      *(s16x8*)&Bg[buf][qrow][(qcol0 + 8) ^ qsw] = dq8(wG1, s2, c2);  \
    } else {                                                          \
      *(s16x8*)&Bg[buf][qrow][(qcol0 + 0) ^ qsw] = dq_compute(qG[0], qG[1], sG, zG); \
      *(s16x8*)&Bg[buf][qrow][(qcol0 + 8) ^ qsw] = dq_compute(qG[2], qG[3], sG, zG); \
    }                                                                 \
    if (PKU) {                                                        \
      __half h3 = __float2half(sU);                                   \
      __half2 s3 = __halves2half2(h3, h3);                            \
      __half h4 = __float2half(-(64.f + zU) * sU);                    \
      __half2 c3 = __halves2half2(h4, h4);                            \
      *(s16x8*)&Bu[buf][qrow][(qcol0 + 0) ^ qsw] = dq8(wU0, s3, c3);  \
      *(s16x8*)&Bu[buf][qrow][(qcol0 + 8) ^ qsw] = dq8(wU1, s3, c3);  \
    } else {                                                          \
      *(s16x8*)&Bu[buf][qrow][(qcol0 + 0) ^ qsw] = dq_compute(qU[0], qU[1], sU, zU); \
      *(s16x8*)&Bu[buf][qrow][(qcol0 + 8) ^ qsw] = dq_compute(qU[2], qU[3], sU, zU); \
    }                                                                 \
  }
#define MFMA_BUF(buf)                                                 \
  {                                                                   \
    __builtin_amdgcn_s_setprio(1);                                    \
    _Pragma("unroll")                                                 \
    for (int kk = 0; kk < 2; ++kk) {                                  \
      const int cbase = (kk * 32 + lq * 8) ^ rsw;                     \
      f16x8 af[4];                                                    \
      _Pragma("unroll")                                               \
      for (int i = 0; i < 4; ++i)                                     \
        af[i] = *(const f16x8*)&As[buf][wm + i * 16 + l15][cbase];    \
      _Pragma("unroll")                                               \
      for (int j = 0; j < 4; ++j) {                                   \
        f16x8 bg = *(const f16x8*)&Bg[buf][wn + j * 16 + l15][cbase]; \
        f16x8 bu = *(const f16x8*)&Bu[buf][wn + j * 16 + l15][cbase]; \
        _Pragma("unroll")                                             \
        for (int i = 0; i < 4; ++i) {                                 \
          accg[i][j] = __builtin_amdgcn_mfma_f32_16x16x32_f16(af[i], bg, accg[i][j], 0, 0, 0); \
          accu[i][j] = __builtin_amdgcn_mfma_f32_16x16x32_f16(af[i], bu, accu[i][j], 0, 0, 0); \
        }                                                             \
      }                                                               \
    }                                                                 \
    __builtin_amdgcn_s_setprio(0);                                    \
  }

  const int nt = H / 64;
  STAGE_A(0, 0)
  LOAD_Q(0)
  WRITE_B(0)
  __syncthreads();

  int p = 0;
  for (int t = 0; t < nt; ++t) {
    if (t + 1 < nt) {
      STAGE_A(p ^ 1, (t + 1) * 64)
      LOAD_Q((t + 1) * 64)
    }
    MFMA_BUF(p)
    if (t + 1 < nt) WRITE_B(p ^ 1)
    __syncthreads();
    p ^= 1;
  }
#undef STAGE_A
#undef LOAD_Q
#undef WRITE_B
#undef MFMA_BUF

  // ---- epilogue: h = silu(g)*u ----
#pragma unroll
  for (int i = 0; i < 4; ++i)
#pragma unroll
    for (int j = 0; j < 4; ++j)
#pragma unroll
      for (int r = 0; r < 4; ++r) {
        const int row = m0 + wm + i * 16 + lq * 4 + r;
        const int col = n0 + wn + j * 16 + l15;
        float g = accg[i][j][r];
        float u = accu[i][j][r];
        float hv = (g / (1.f + __expf(-g))) * u;
        Pan[(size_t)row * I + col] = __float2half(hv);
      }
}

// ---------------------------------------------------------------------------
// Down GEMM: out = h @ Wd^T. A via global_load_lds, 2-deep Q prefetch.
// ---------------------------------------------------------------------------
template <int PK>
__global__ __launch_bounds__(512, 2)
void down_kernel(const __half* __restrict__ Hws,
                 const int* __restrict__ Qd, const uint32_t* __restrict__ QdP,
                 const float* __restrict__ Sd, const float* __restrict__ Zd,
                 float* __restrict__ Out, int mbs) {
  constexpr int K = 11008, N = 4096, G = 86;
  const int wg = xcd_swz(blockIdx.x, gridDim.x);
  const int mb = wg % mbs;
  const int nb = wg / mbs;
  const int m0 = mb * 256, n0 = nb * 128;
  const int tid = threadIdx.x;
  const int lane = tid & 63;
  const int wave = tid >> 6;
  const int wm = (wave >> 1) * 64, wn = (wave & 1) * 64;
  const int l15 = lane & 15, lq = lane >> 4;
  const int rsw = (l15 & 7) << 3;

  __shared__ __half As[2][256][64];
  __shared__ __half Bs[2][128][64];

  f32x4 acc[4][4];
#pragma unroll
  for (int i = 0; i < 4; ++i)
#pragma unroll
    for (int j = 0; j < 4; ++j) acc[i][j] = {0.f, 0.f, 0.f, 0.f};

  const int arowD = tid >> 3;
  const int acolD = (((tid & 7) ^ ((tid >> 3) & 7)) << 3);
  const int qrow = tid >> 2, qcol0 = (tid & 3) * 16, qsw = (qrow & 7) << 3;
  const int*      qP  = Qd  + (size_t)(n0 + qrow) * K + qcol0;
  const uint32_t* qPp = QdP + (size_t)(n0 + qrow) * (K / 8) + (tid & 3) * 2;
  const float* sP = Sd + (size_t)(n0 + qrow) * G;
  const float* zP = Zd + (size_t)(n0 + qrow) * G;

  int4 qA[4], qB[4];
  uint32_t wA0, wA1, wB0, wB1;
  float sA, zA, sB, zB;

#define STAGE_A(buf, kk)                                              \
  {                                                                   \
    const int _k = (kk);                                              \
    _Pragma("unroll")                                                 \
    for (int c = 0; c < 4; ++c) {                                     \
      const __half* src = Hws + (size_t)(m0 + c * 64 + arowD) * K + _k + acolD; \
      __half* dst = &As[buf][0][0] + (size_t)(c * 512 + tid) * 8;     \
      __builtin_amdgcn_global_load_lds((const __attribute__((address_space(1))) void*)src, \
                                       (__attribute__((address_space(3))) void*)dst, 16, 0, 0); \
    }                                                                 \
  }
#define LOAD_Q(set, kk)                                               \
  {                                                                   \
    const int _k = (kk);                                              \
    if (PK) {                                                         \
      w##set##0 = qPp[_k >> 3]; w##set##1 = qPp[(_k >> 3) + 1];       \
    } else {                                                          \
      _Pragma("unroll")                                               \
      for (int i = 0; i < 4; ++i) q##set[i] = ((const int4*)(qP + _k))[i]; \
    }                                                                 \
    s##set = sP[_k >> 7]; z##set = zP[_k >> 7];                       \
  }
#define WRITE_B(buf, set)                                             \
  {                                                                   \
    if (PK) {                                                         \
      __half hs = __float2half(s##set);                               \
      __half2 s2 = __halves2half2(hs, hs);                            \
      __half hc = __float2half(-(64.f + z##set) * s##set);            \
      __half2 c2 = __halves2half2(hc, hc);                            \
      *(s16x8*)&Bs[buf][qrow][(qcol0 + 0) ^ qsw] = dq8(w##set##0, s2, c2); \
      *(s16x8*)&Bs[buf][qrow][(qcol0 + 8) ^ qsw] = dq8(w##set##1, s2, c2); \
    } else {                                                          \
      *(s16x8*)&Bs[buf][qrow][(qcol0 + 0) ^ qsw] = dq_compute(q##set[0], q##set[1], s##set, z##set); \
      *(s16x8*)&Bs[buf][qrow][(qcol0 + 8) ^ qsw] = dq_compute(q##set[2], q##set[3], s##set, z##set); \
    }                                                                 \
  }
#define MFMA_BUF(buf)                                                 \
  {                                                                   \
    __builtin_amdgcn_s_setprio(1);                                    \
    _Pragma("unroll")                                                 \
    for (int kk = 0; kk < 2; ++kk) {                                  \
      const int cbase = (kk * 32 + lq * 8) ^ rsw;                     \
      f16x8 af[4];                                                    \
      _Pragma("unroll")                                               \
      for (int i = 0; i < 4; ++i)                                     \
        af[i] = *(const f16x8*)&As[buf][wm + i * 16 + l15][cbase];    \
      _Pragma("unroll")                                               \
      for (int j = 0; j < 4; ++j) {                                   \
        f16x8 bf = *(const f16x8*)&Bs[buf][wn + j * 16 + l15][cbase]; \
        _Pragma("unroll")                                             \
        for (int i = 0; i < 4; ++i)                                   \
          acc[i][j] = __builtin_amdgcn_mfma_f32_16x16x32_f16(af[i], bf, acc[i][j], 0, 0, 0); \
      }                                                               \
    }                                                                 \
    __builtin_amdgcn_s_setprio(0);                                    \
  }

  const int nt = K / 64;  // 172, even
  STAGE_A(0, 0)
  LOAD_Q(A, 0)
  LOAD_Q(B, 64)
  WRITE_B(0, A)
  __syncthreads();

  for (int t = 0; t < nt; t += 2) {
    if (t + 1 < nt) STAGE_A(1, (t + 1) * 64)
    if (t + 2 < nt) LOAD_Q(A, (t + 2) * 64)
    MFMA_BUF(0)
    if (t + 1 < nt) WRITE_B(1, B)
    __syncthreads();
    if (t + 2 < nt) STAGE_A(0, (t + 2) * 64)
    if (t + 3 < nt) LOAD_Q(B, (t + 3) * 64)
    MFMA_BUF(1)
    if (t + 2 < nt) WRITE_B(0, A)
    __syncthreads();
  }
#undef STAGE_A
#undef LOAD_Q
#undef WRITE_B
#undef MFMA_BUF

#pragma unroll
  for (int i = 0; i < 4; ++i)
#pragma unroll
    for (int j = 0; j < 4; ++j)
#pragma unroll
      for (int r = 0; r < 4; ++r) {
        const int row = m0 + wm + i * 16 + lq * 4 + r;
        const int col = n0 + wn + j * 16 + l15;
        Out[(size_t)row * N + col] = acc[i][j][r];
      }
}

// ---------------------------------------------------------------------------
extern "C" void kernel_launch(void* const* d_in, const int* in_sizes, int n_in,
                              void* d_out, int out_size, void* d_ws, size_t ws_size,
                              hipStream_t stream) {
  const float* x  = (const float*)d_in[0];
  const int* qg   = (const int*)d_in[1];
  const int* qu   = (const int*)d_in[2];
  const int* qd   = (const int*)d_in[3];
  const float* sg = (const float*)d_in[4];
  const float* zg = (const float*)d_in[5];
  const float* su = (const float*)d_in[6];
  const float* zu = (const float*)d_in[7];
  const float* sd = (const float*)d_in[8];
  const float* zd = (const float*)d_in[9];
  float* out = (float*)d_out;

  const int M = 8192, H = 4096, I = 11008;
  const long N8 = (long)I * H / 8;   // = exactly 1376 out-rows per matrix

  // Packed at d_out bottom; chunks DESCENDING so down's writes hit them last.
  // Pd rows 0..1375 (used by most downs), Pg 1376..2751, Pu 2752..4127.
  const int PD_MAX = 1375, PG_MAX = 2751, PU_MAX = 4127;
  uint32_t* Pd = (uint32_t*)d_out;
  uint32_t* Pg = Pd + N8;
  uint32_t* Pu = Pg + N8;

  pack_kernel<<<2048, 256, 0, stream>>>(qd, Pd, N8);
  pack_kernel<<<2048, 256, 0, stream>>>(qg, Pg, N8);
  pack_kernel<<<2048, 256, 0, stream>>>(qu, Pu, N8);

  // ws holds ONLY the h panel; wsx lives in d_out (upper rows of own chunk).
  // Mc=2048 -> gateup grid 688 (89.6% round-eff), down grid exactly 256.
  long mc = (long)(ws_size / ((size_t)I * 2));
  mc &= ~255L;
  if (mc > 2048) mc = 2048;
  if (mc < 256) mc = 256;
  const int Mc = (int)mc;
  __half* wsh = (__half*)d_ws;

  // chunk table (ascending); process descending
  int mb_arr[64], mbs_arr[64];
  int nch = 0;
  for (int mb = 0; mb < M; mb += Mc) {
    mb_arr[nch] = mb;
    mbs_arr[nch] = ((M - mb < Mc) ? (M - mb) : Mc) / 256;
    ++nch;
  }

  int destr = M;  // lowest row already written/clobbered in d_out
  for (int c = nch - 1; c >= 0; --c) {
    const int mbase = mb_arr[c];
    const int mbs = mbs_arr[c];
    const int rows = mbs * 256;
    // wsx(c): fp16 x-chunk in d_out upper rows of chunk c (rows/2 out-rows)
    const int xrows = rows / 2;
    const int wsxlo = mbase + rows - xrows;
    __half* wsx = (__half*)(out + (size_t)wsxlo * H);

    cvt_f32_to_f16_kernel<<<1024, 256, 0, stream>>>(
        x + (size_t)mbase * H, wsx, (long)rows * H);
    if (wsxlo < destr) destr = wsxlo;   // wsx write clobbers these rows

    const bool g_pk = (PG_MAX < destr);
    const bool u_pk = (PU_MAX < destr);
    const bool d_pk = (PD_MAX < destr) && (PD_MAX < mbase);

    if (g_pk && u_pk)
      gateup_kernel<1, 1><<<mbs * (I / 128), 512, 0, stream>>>(
          wsx, qg, Pg, qu, Pu, sg, zg, su, zu, wsh, mbs);
    else if (g_pk)
      gateup_kernel<1, 0><<<mbs * (I / 128), 512, 0, stream>>>(
          wsx, qg, Pg, qu, Pu, sg, zg, su, zu, wsh, mbs);
    else
      gateup_kernel<0, 0><<<mbs * (I / 128), 512, 0, stream>>>(
          wsx, qg, Pg, qu, Pu, sg, zg, su, zu, wsh, mbs);

    if (d_pk)
      down_kernel<1><<<mbs * 32, 512, 0, stream>>>(
          wsh, qd, Pd, sd, zd, out + (size_t)mbase * H, mbs);
    else
      down_kernel<0><<<mbs * 32, 512, 0, stream>>>(
          wsh, qd, Pd, sd, zd, out + (size_t)mbase * H, mbs);

    if (mbase < destr) destr = mbase;   // down wrote this chunk
  }
}